// Round 2
// baseline (1385.472 us; speedup 1.0000x reference)
//
#include <hip/hip_runtime.h>
#include <hip/hip_bf16.h>

// AttributeGNN fused kernel, bf16 MFMA, fp32 accumulate.
// B=16384 batch, A=16 edge types, D=256 embedding.
// R2: a-split grid (512x2), T in registers, 48KB LDS, async edge prefetch.

typedef __bf16 bf16_t;
typedef __bf16 bf16x4 __attribute__((ext_vector_type(4)));
typedef __bf16 bf16x8 __attribute__((ext_vector_type(8)));
typedef float f32x4 __attribute__((ext_vector_type(4)));

#define NB 16384
#define NA 16
#define ND 256
#define ABLK 8   // edge types per block (NA/2)

// XOR swizzle for bf16 LDS tiles [32][256] (row stride 512B): spreads 8 rows
// across 8 distinct 16B bank-groups; 16-lane column reads become 2-way (free).
__device__ __forceinline__ int swz(int r, int c) {
    return r * 256 + (c ^ ((r & 7) << 3));
}

// 32(M) x 256(K) x 64(N-slice) bt-GEMM step: A from swizzled LDS (bf16),
// B row-major [N][K] bf16 from global (L2-resident weights).
// C/D layout per m89: col = lane&15, row = (lane>>4)*4 + j.
__device__ __forceinline__ void gemm_tile(const bf16_t* a_lds, const bf16_t* __restrict__ Bg,
                                          f32x4 acc[2][4], int lane, int n0w)
{
    const int lr = lane & 15, lhi = lane >> 4;
#pragma unroll
    for (int ks = 0; ks < 8; ++ks) {
        const int kc = ks * 32 + lhi * 8;
        bf16x8 af0 = *(const bf16x8*)&a_lds[swz(lr, kc)];
        bf16x8 af1 = *(const bf16x8*)&a_lds[swz(16 + lr, kc)];
#pragma unroll
        for (int ni = 0; ni < 4; ++ni) {
            bf16x8 bfr = *(const bf16x8*)&Bg[(n0w + ni * 16 + lr) * 256 + kc];
            acc[0][ni] = __builtin_amdgcn_mfma_f32_16x16x32_bf16(af0, bfr, acc[0][ni], 0, 0, 0);
            acc[1][ni] = __builtin_amdgcn_mfma_f32_16x16x32_bf16(af1, bfr, acc[1][ni], 0, 0, 0);
        }
    }
}

// W_agg [D][2D] fp32 -> W1 [D][D] bf16 (k-major), W2 [D][D] bf16.
__global__ void prep_w(const float* __restrict__ W, bf16_t* __restrict__ W1, bf16_t* __restrict__ W2)
{
    int o = blockIdx.x;
    int k = threadIdx.x;
    W1[o * 256 + k] = (bf16_t)W[o * 512 + k];
    W2[o * 256 + k] = (bf16_t)W[o * 512 + 256 + k];
}

// P[a][i][j] fp32 -> Pt[a][j][i] bf16 via LDS 32x32 tile transpose.
__global__ void transpose_P(const float* __restrict__ Pf, const float* __restrict__ Pb,
                            bf16_t* __restrict__ Pft, bf16_t* __restrict__ Pbt)
{
    __shared__ float t[32][33];
    int blk = blockIdx.x;
    int mat = blk >> 10;
    int rest = blk & 1023;
    int a = rest >> 6;
    int tile = rest & 63;
    int i0 = (tile >> 3) * 32;
    int j0 = (tile & 7) * 32;
    const float* src = (mat ? Pb : Pf) + a * 65536;
    bf16_t* dst = (mat ? Pbt : Pft) + a * 65536;
    int r = threadIdx.x >> 5, c = threadIdx.x & 31;
#pragma unroll
    for (int it = 0; it < 4; ++it)
        t[r + 8 * it][c] = src[(i0 + r + 8 * it) * 256 + j0 + c];
    __syncthreads();
#pragma unroll
    for (int it = 0; it < 4; ++it)
        dst[(j0 + r + 8 * it) * 256 + i0 + c] = (bf16_t)t[c][r + 8 * it];
}

__global__ __launch_bounds__(256, 3)
void fused_main(const float* __restrict__ img, const float* __restrict__ bias,
                const float* __restrict__ edge,
                const bf16_t* __restrict__ W1, const bf16_t* __restrict__ W2,
                const bf16_t* __restrict__ Pf, const bf16_t* __restrict__ Pb,
                const float* __restrict__ sw, float* __restrict__ out,
                float* __restrict__ part)
{
    __shared__ bf16_t E[2][32 * 256];  // 2 x 16 KB: edge double-buffer; consumed buf reused for attr(r)
    __shared__ bf16_t G[32 * 256];     // 16 KB: agg tile

    const int tid = threadIdx.x;
    const int lane = tid & 63;
    const int wave = tid >> 6;
    const int n0w = wave * 64;
    const int brow0 = blockIdx.x * 32;
    const int a0 = blockIdx.y * ABLK;
    const int lr = lane & 15;
    const int lhi = lane >> 4;
    const int srr = tid >> 6;          // staging row base 0..3
    const int sc4 = (tid & 63) * 4;    // staging col 0..252

    f32x4 e0, e1, e2, e3, e4, e5, e6, e7;

#define EDGE_ISSUE(A_) { \
    const float* ep = edge + (size_t)brow0 * (NA * ND) + (size_t)(A_) * ND + sc4; \
    e0 = *(const f32x4*)(ep + (size_t)(srr +  0) * (NA * ND)); \
    e1 = *(const f32x4*)(ep + (size_t)(srr +  4) * (NA * ND)); \
    e2 = *(const f32x4*)(ep + (size_t)(srr +  8) * (NA * ND)); \
    e3 = *(const f32x4*)(ep + (size_t)(srr + 12) * (NA * ND)); \
    e4 = *(const f32x4*)(ep + (size_t)(srr + 16) * (NA * ND)); \
    e5 = *(const f32x4*)(ep + (size_t)(srr + 20) * (NA * ND)); \
    e6 = *(const f32x4*)(ep + (size_t)(srr + 24) * (NA * ND)); \
    e7 = *(const f32x4*)(ep + (size_t)(srr + 28) * (NA * ND)); }

#define EDGE_COMMIT(B_) { \
    bf16_t* eb = &E[B_][0]; \
    bf16x4 s; \
    s = (bf16x4){(bf16_t)e0.x,(bf16_t)e0.y,(bf16_t)e0.z,(bf16_t)e0.w}; *(bf16x4*)&eb[swz(srr +  0, sc4)] = s; \
    s = (bf16x4){(bf16_t)e1.x,(bf16_t)e1.y,(bf16_t)e1.z,(bf16_t)e1.w}; *(bf16x4*)&eb[swz(srr +  4, sc4)] = s; \
    s = (bf16x4){(bf16_t)e2.x,(bf16_t)e2.y,(bf16_t)e2.z,(bf16_t)e2.w}; *(bf16x4*)&eb[swz(srr +  8, sc4)] = s; \
    s = (bf16x4){(bf16_t)e3.x,(bf16_t)e3.y,(bf16_t)e3.z,(bf16_t)e3.w}; *(bf16x4*)&eb[swz(srr + 12, sc4)] = s; \
    s = (bf16x4){(bf16_t)e4.x,(bf16_t)e4.y,(bf16_t)e4.z,(bf16_t)e4.w}; *(bf16x4*)&eb[swz(srr + 16, sc4)] = s; \
    s = (bf16x4){(bf16_t)e5.x,(bf16_t)e5.y,(bf16_t)e5.z,(bf16_t)e5.w}; *(bf16x4*)&eb[swz(srr + 20, sc4)] = s; \
    s = (bf16x4){(bf16_t)e6.x,(bf16_t)e6.y,(bf16_t)e6.z,(bf16_t)e6.w}; *(bf16x4*)&eb[swz(srr + 24, sc4)] = s; \
    s = (bf16x4){(bf16_t)e7.x,(bf16_t)e7.y,(bf16_t)e7.z,(bf16_t)e7.w}; *(bf16x4*)&eb[swz(srr + 28, sc4)] = s; }

    // ---- prologue: T = img @ W1^T + bias, kept in registers (a-invariant) ----
#pragma unroll
    for (int it = 0; it < 8; ++it) {
        int r = srr + it * 4;
        f32x4 v = *(const f32x4*)&img[(size_t)(brow0 + r) * ND + sc4];
        bf16x4 s = {(bf16_t)v.x, (bf16_t)v.y, (bf16_t)v.z, (bf16_t)v.w};
        *(bf16x4*)&E[0][swz(r, sc4)] = s;
    }
    __syncthreads();

    EDGE_ISSUE(a0);  // prefetch first edge tile; consumed after T-GEMM

    f32x4 T[2][4];
#pragma unroll
    for (int ni = 0; ni < 4; ++ni) {
        float bz = bias[n0w + ni * 16 + lr];
        T[0][ni] = (f32x4){bz, bz, bz, bz};
        T[1][ni] = (f32x4){bz, bz, bz, bz};
    }
    gemm_tile(&E[0][0], W1, T, lane, n0w);
    __syncthreads();                   // all waves done reading img from E[0]

    EDGE_COMMIT(0);                    // data-dep forces vmcnt wait on edge regs
    __syncthreads();

    f32x4 indiv[2][4];
#pragma unroll
    for (int mi = 0; mi < 2; ++mi)
#pragma unroll
        for (int ni = 0; ni < 4; ++ni)
            indiv[mi][ni] = (f32x4){0.f, 0.f, 0.f, 0.f};

    for (int a = a0; a < a0 + ABLK; ++a) {
        const int cur = a & 1;
        bf16_t* Ecur = &E[cur][0];
        f32x4 acc[2][4];

        // ---- phase 1: agg = T + edge @ W2^T; prefetch edge(a+1) under it ----
        if (a + 1 < a0 + ABLK) EDGE_ISSUE(a + 1);
#pragma unroll
        for (int mi = 0; mi < 2; ++mi)
#pragma unroll
            for (int ni = 0; ni < 4; ++ni)
                acc[mi][ni] = T[mi][ni];
        gemm_tile(Ecur, W2, acc, lane, n0w);
#pragma unroll
        for (int mi = 0; mi < 2; ++mi)
#pragma unroll
            for (int ni = 0; ni < 4; ++ni)
#pragma unroll
                for (int j = 0; j < 4; ++j)
                    G[swz(mi * 16 + lhi * 4 + j, n0w + ni * 16 + lr)] = (bf16_t)acc[mi][ni][j];
        if (a + 1 < a0 + ABLK) EDGE_COMMIT(cur ^ 1);  // E[cur^1] safe: last read 2 barriers ago
        __syncthreads();

        // ---- phase 2: attr = agg @ P_fwd[a]; write attr out + bf16 into Ecur ----
#pragma unroll
        for (int mi = 0; mi < 2; ++mi)
#pragma unroll
            for (int ni = 0; ni < 4; ++ni)
                acc[mi][ni] = (f32x4){0.f, 0.f, 0.f, 0.f};
        gemm_tile(&G[0], Pf + (size_t)a * 65536, acc, lane, n0w);
        {
            float* op = out + (size_t)brow0 * (NA * ND) + (size_t)a * ND;
#pragma unroll
            for (int mi = 0; mi < 2; ++mi)
#pragma unroll
                for (int ni = 0; ni < 4; ++ni)
#pragma unroll
                    for (int j = 0; j < 4; ++j) {
                        int r = mi * 16 + lhi * 4 + j;
                        int c = n0w + ni * 16 + lr;
                        float v = acc[mi][ni][j];
                        op[(size_t)r * (NA * ND) + c] = v;
                        Ecur[swz(r, c)] = (bf16_t)v;
                    }
        }
        __syncthreads();

        // ---- phase 3: proj = relu(attr @ P_bwd[a]); indiv += proj * sw[a] ----
#pragma unroll
        for (int mi = 0; mi < 2; ++mi)
#pragma unroll
            for (int ni = 0; ni < 4; ++ni)
                acc[mi][ni] = (f32x4){0.f, 0.f, 0.f, 0.f};
        gemm_tile(Ecur, Pb + (size_t)a * 65536, acc, lane, n0w);
        const float swa = sw[a];
#pragma unroll
        for (int mi = 0; mi < 2; ++mi)
#pragma unroll
            for (int ni = 0; ni < 4; ++ni)
#pragma unroll
                for (int j = 0; j < 4; ++j)
                    indiv[mi][ni][j] += fmaxf(acc[mi][ni][j], 0.f) * swa;
        __syncthreads();
    }

    // half 0 -> out directly; half 1 -> ws partial (summed by reduce_indiv)
    float* ind = (blockIdx.y == 0) ? (out + (size_t)NB * NA * ND) : part;
#pragma unroll
    for (int mi = 0; mi < 2; ++mi)
#pragma unroll
        for (int ni = 0; ni < 4; ++ni)
#pragma unroll
            for (int j = 0; j < 4; ++j) {
                int r = mi * 16 + lhi * 4 + j;
                int c = n0w + ni * 16 + lr;
                ind[(size_t)(brow0 + r) * ND + c] = indiv[mi][ni][j];
            }
#undef EDGE_ISSUE
#undef EDGE_COMMIT
}

__global__ void reduce_indiv(float* __restrict__ outI, const float* __restrict__ part)
{
    size_t i = ((size_t)blockIdx.x * 256 + threadIdx.x) * 4;
    f32x4 a = *(const f32x4*)&outI[i];
    f32x4 b = *(const f32x4*)&part[i];
    a.x += b.x; a.y += b.y; a.z += b.z; a.w += b.w;
    *(f32x4*)&outI[i] = a;
}

extern "C" void kernel_launch(void* const* d_in, const int* in_sizes, int n_in,
                              void* d_out, int out_size, void* d_ws, size_t ws_size,
                              hipStream_t stream)
{
    const float* img  = (const float*)d_in[0];
    const float* edge = (const float*)d_in[1];
    const float* Wagg = (const float*)d_in[2];
    const float* bagg = (const float*)d_in[3];
    const float* Pf   = (const float*)d_in[4];
    const float* Pb   = (const float*)d_in[5];
    const float* sw   = (const float*)d_in[6];
    float* out = (float*)d_out;

    char* ws = (char*)d_ws;
    bf16_t* W1   = (bf16_t*)(ws);                      // 128 KB
    bf16_t* W2   = (bf16_t*)(ws + 131072);             // 128 KB
    bf16_t* Pft  = (bf16_t*)(ws + 262144);             // 2 MB
    bf16_t* Pbt  = (bf16_t*)(ws + 2359296);            // 2 MB
    float*  part = (float*)(ws + 4456448);             // 16 MB indiv partial (half 1)

    prep_w<<<256, 256, 0, stream>>>(Wagg, W1, W2);
    transpose_P<<<2048, 256, 0, stream>>>(Pf, Pb, Pft, Pbt);
    fused_main<<<dim3(512, 2), 256, 0, stream>>>(img, bagg, edge, W1, W2, Pft, Pbt, sw, out, part);
    reduce_indiv<<<4096, 256, 0, stream>>>(out + (size_t)NB * NA * ND, part);
}

// Round 3
// 718.636 us; speedup vs baseline: 1.9279x; 1.9279x over previous
//
#include <hip/hip_runtime.h>
#include <hip/hip_bf16.h>

// AttributeGNN fused kernel, bf16 MFMA, fp32 accumulate.
// B=16384, A=16, D=256.
// R3: BM=64 / 512-thr / 8-wave blocks, single weight working set (no a-split),
//     depth-3 register prefetch of B-fragments, T14 edge reg-prefetch.

typedef __bf16 bf16_t;
typedef __bf16 bf16x4 __attribute__((ext_vector_type(4)));
typedef __bf16 bf16x8 __attribute__((ext_vector_type(8)));
typedef float f32x4 __attribute__((ext_vector_type(4)));

#define NB 16384
#define NA 16
#define ND 256
#define BM 64   // rows per block

// XOR swizzle for bf16 LDS tiles [*][256] (row stride 512B): spreads 8-row
// stripes across 8 distinct 16B slots; 16-lane column reads -> 2-way (free).
__device__ __forceinline__ int swz(int r, int c) {
    return r * 256 + (c ^ ((r & 7) << 3));
}

// Per-wave 32(M)x256(K)x64(N) GEMM slice. A from swizzled LDS; B row-major
// [N][K] bf16 from global (L2-resident weights) with depth-3 register pipeline.
// C/D layout per m89: col = lane&15, row = (lane>>4)*4 + j.
__device__ __forceinline__ void gemm64(const bf16_t* a_lds, const bf16_t* __restrict__ Bg,
                                       f32x4 acc[2][4], int wr, int wc, int lane)
{
    const int lr = lane & 15, lhi = lane >> 4;
    const int ar0 = wr * 32 + lr;
    const bf16_t* brow = Bg + (wc * 64 + lr) * 256 + lhi * 8;
    bf16x8 bq[3][4];
#pragma unroll
    for (int p = 0; p < 3; ++p)
#pragma unroll
        for (int ni = 0; ni < 4; ++ni)
            bq[p][ni] = *(const bf16x8*)&brow[ni * 4096 + p * 32];
#pragma unroll
    for (int ks = 0; ks < 8; ++ks) {
        const int kc = ks * 32 + lhi * 8;
        bf16x8 af0 = *(const bf16x8*)&a_lds[swz(ar0, kc)];
        bf16x8 af1 = *(const bf16x8*)&a_lds[swz(ar0 + 16, kc)];
#pragma unroll
        for (int ni = 0; ni < 4; ++ni) {
            acc[0][ni] = __builtin_amdgcn_mfma_f32_16x16x32_bf16(af0, bq[ks % 3][ni], acc[0][ni], 0, 0, 0);
            acc[1][ni] = __builtin_amdgcn_mfma_f32_16x16x32_bf16(af1, bq[ks % 3][ni], acc[1][ni], 0, 0, 0);
        }
        if (ks + 3 < 8) {
#pragma unroll
            for (int ni = 0; ni < 4; ++ni)
                bq[ks % 3][ni] = *(const bf16x8*)&brow[ni * 4096 + (ks + 3) * 32];
        }
    }
}

// W_agg [D][2D] fp32 -> W1 [D][D] bf16 (k-major), W2 [D][D] bf16.
__global__ void prep_w(const float* __restrict__ W, bf16_t* __restrict__ W1, bf16_t* __restrict__ W2)
{
    int o = blockIdx.x;
    int k = threadIdx.x;
    W1[o * 256 + k] = (bf16_t)W[o * 512 + k];
    W2[o * 256 + k] = (bf16_t)W[o * 512 + 256 + k];
}

// P[a][i][j] fp32 -> Pt[a][j][i] bf16 via LDS 32x32 tile transpose.
__global__ void transpose_P(const float* __restrict__ Pf, const float* __restrict__ Pb,
                            bf16_t* __restrict__ Pft, bf16_t* __restrict__ Pbt)
{
    __shared__ float t[32][33];
    int blk = blockIdx.x;
    int mat = blk >> 10;
    int rest = blk & 1023;
    int a = rest >> 6;
    int tile = rest & 63;
    int i0 = (tile >> 3) * 32;
    int j0 = (tile & 7) * 32;
    const float* src = (mat ? Pb : Pf) + a * 65536;
    bf16_t* dst = (mat ? Pbt : Pft) + a * 65536;
    int r = threadIdx.x >> 5, c = threadIdx.x & 31;
#pragma unroll
    for (int it = 0; it < 4; ++it)
        t[r + 8 * it][c] = src[(i0 + r + 8 * it) * 256 + j0 + c];
    __syncthreads();
#pragma unroll
    for (int it = 0; it < 4; ++it)
        dst[(j0 + r + 8 * it) * 256 + i0 + c] = (bf16_t)t[c][r + 8 * it];
}

__global__ __launch_bounds__(512, 2)
void fused_main(const float* __restrict__ img, const float* __restrict__ bias,
                const float* __restrict__ edge,
                const bf16_t* __restrict__ W1, const bf16_t* __restrict__ W2,
                const bf16_t* __restrict__ Pf, const bf16_t* __restrict__ Pb,
                const float* __restrict__ sw, float* __restrict__ out)
{
    __shared__ bf16_t E[2][BM * 256];  // 2 x 32 KB edge double-buffer
    __shared__ bf16_t G[BM * 256];     // 32 KB agg tile
    __shared__ bf16_t R[BM * 256];     // 32 KB attr tile

    const int tid = threadIdx.x;
    const int lane = tid & 63;
    const int wid = tid >> 6;
    const int wr = wid >> 2;            // 0..1: 32-row band
    const int wc = wid & 3;             // 0..3: 64-col slice
    const int lr = lane & 15;
    const int lhi = lane >> 4;
    const int brow0 = blockIdx.x * BM;
    const int srr = tid >> 6;           // staging row base 0..7
    const int sc4 = (tid & 63) * 4;     // staging col 0..252

    f32x4 ev[8];

#define EDGE_ISSUE(A_) { \
    const float* ep = edge + (size_t)(brow0 + srr) * (NA * ND) + (size_t)(A_) * ND + sc4; \
    _Pragma("unroll") \
    for (int it = 0; it < 8; ++it) \
        ev[it] = *(const f32x4*)(ep + (size_t)it * 8 * (NA * ND)); }

#define EDGE_COMMIT(B_) { \
    bf16_t* eb = &E[B_][0]; \
    _Pragma("unroll") \
    for (int it = 0; it < 8; ++it) { \
        bf16x4 s = {(bf16_t)ev[it].x, (bf16_t)ev[it].y, (bf16_t)ev[it].z, (bf16_t)ev[it].w}; \
        *(bf16x4*)&eb[swz(srr + it * 8, sc4)] = s; \
    } }

    // ---- prologue: stage img -> E[0], T = img @ W1^T + bias (kept in regs) ----
#pragma unroll
    for (int it = 0; it < 8; ++it) {
        int r = srr + it * 8;
        f32x4 v = *(const f32x4*)&img[(size_t)(brow0 + r) * ND + sc4];
        bf16x4 s = {(bf16_t)v.x, (bf16_t)v.y, (bf16_t)v.z, (bf16_t)v.w};
        *(bf16x4*)&E[0][swz(r, sc4)] = s;
    }
    __syncthreads();

    EDGE_ISSUE(0);

    f32x4 T[2][4];
#pragma unroll
    for (int ni = 0; ni < 4; ++ni) {
        float bz = bias[wc * 64 + ni * 16 + lr];
        T[0][ni] = (f32x4){bz, bz, bz, bz};
        T[1][ni] = (f32x4){bz, bz, bz, bz};
    }
    gemm64(&E[0][0], W1, T, wr, wc, lane);
    __syncthreads();           // all waves done reading img from E[0]

    EDGE_COMMIT(0);
    __syncthreads();

    f32x4 indiv[2][4];
#pragma unroll
    for (int mi = 0; mi < 2; ++mi)
#pragma unroll
        for (int ni = 0; ni < 4; ++ni)
            indiv[mi][ni] = (f32x4){0.f, 0.f, 0.f, 0.f};

    for (int a = 0; a < NA; ++a) {
        const int cur = a & 1;
        f32x4 acc[2][4];

        // ---- phase 1: agg = T + edge @ W2^T; issue edge(a+1) loads under it ----
        if (a + 1 < NA) EDGE_ISSUE(a + 1);
#pragma unroll
        for (int mi = 0; mi < 2; ++mi)
#pragma unroll
            for (int ni = 0; ni < 4; ++ni)
                acc[mi][ni] = T[mi][ni];
        gemm64(&E[cur][0], W2, acc, wr, wc, lane);
#pragma unroll
        for (int mi = 0; mi < 2; ++mi)
#pragma unroll
            for (int ni = 0; ni < 4; ++ni)
#pragma unroll
                for (int j = 0; j < 4; ++j)
                    G[swz(wr * 32 + mi * 16 + lhi * 4 + j, wc * 64 + ni * 16 + lr)] = (bf16_t)acc[mi][ni][j];
        __syncthreads();

        // ---- phase 2: attr = agg @ P_fwd[a] -> out + R ----
#pragma unroll
        for (int mi = 0; mi < 2; ++mi)
#pragma unroll
            for (int ni = 0; ni < 4; ++ni)
                acc[mi][ni] = (f32x4){0.f, 0.f, 0.f, 0.f};
        gemm64(&G[0], Pf + (size_t)a * 65536, acc, wr, wc, lane);
        {
            float* op = out + (size_t)brow0 * (NA * ND) + (size_t)a * ND;
#pragma unroll
            for (int mi = 0; mi < 2; ++mi)
#pragma unroll
                for (int ni = 0; ni < 4; ++ni)
#pragma unroll
                    for (int j = 0; j < 4; ++j) {
                        int r = wr * 32 + mi * 16 + lhi * 4 + j;
                        int c = wc * 64 + ni * 16 + lr;
                        float v = acc[mi][ni][j];
                        op[(size_t)r * (NA * ND) + c] = v;
                        R[swz(r, c)] = (bf16_t)v;
                    }
        }
        __syncthreads();

        // ---- phase 3: proj = relu(attr @ P_bwd[a]); indiv += proj * sw[a];
        //      commit edge(a+1) into the other E buffer ----
#pragma unroll
        for (int mi = 0; mi < 2; ++mi)
#pragma unroll
            for (int ni = 0; ni < 4; ++ni)
                acc[mi][ni] = (f32x4){0.f, 0.f, 0.f, 0.f};
        gemm64(&R[0], Pb + (size_t)a * 65536, acc, wr, wc, lane);
        const float swa = sw[a];
#pragma unroll
        for (int mi = 0; mi < 2; ++mi)
#pragma unroll
            for (int ni = 0; ni < 4; ++ni)
#pragma unroll
                for (int j = 0; j < 4; ++j)
                    indiv[mi][ni][j] += fmaxf(acc[mi][ni][j], 0.f) * swa;
        if (a + 1 < NA) EDGE_COMMIT(cur ^ 1);
        __syncthreads();
    }

    // individual_embeddings
#pragma unroll
    for (int mi = 0; mi < 2; ++mi)
#pragma unroll
        for (int ni = 0; ni < 4; ++ni)
#pragma unroll
            for (int j = 0; j < 4; ++j) {
                int r = wr * 32 + mi * 16 + lhi * 4 + j;
                int c = wc * 64 + ni * 16 + lr;
                out[(size_t)NB * NA * ND + (size_t)(brow0 + r) * ND + c] = indiv[mi][ni][j];
            }
#undef EDGE_ISSUE
#undef EDGE_COMMIT
}

extern "C" void kernel_launch(void* const* d_in, const int* in_sizes, int n_in,
                              void* d_out, int out_size, void* d_ws, size_t ws_size,
                              hipStream_t stream)
{
    const float* img  = (const float*)d_in[0];
    const float* edge = (const float*)d_in[1];
    const float* Wagg = (const float*)d_in[2];
    const float* bagg = (const float*)d_in[3];
    const float* Pf   = (const float*)d_in[4];
    const float* Pb   = (const float*)d_in[5];
    const float* sw   = (const float*)d_in[6];
    float* out = (float*)d_out;

    char* ws = (char*)d_ws;
    bf16_t* W1  = (bf16_t*)(ws);                       // 128 KB
    bf16_t* W2  = (bf16_t*)(ws + 131072);              // 128 KB
    bf16_t* Pft = (bf16_t*)(ws + 262144);              // 2 MB
    bf16_t* Pbt = (bf16_t*)(ws + 2359296);             // 2 MB

    prep_w<<<256, 256, 0, stream>>>(Wagg, W1, W2);
    transpose_P<<<2048, 256, 0, stream>>>(Pf, Pb, Pft, Pbt);
    fused_main<<<NB / BM, 512, 0, stream>>>(img, bagg, edge, W1, W2, Pft, Pbt, sw, out);
}

// Round 4
// 654.107 us; speedup vs baseline: 2.1181x; 1.0987x over previous
//
#include <hip/hip_runtime.h>
#include <hip/hip_bf16.h>

// AttributeGNN fused kernel, bf16 MFMA, fp32 accumulate.
// B=16384, A=16, D=256.
// R4: R3 + non-temporal hints on all streaming traffic (keep weights L2-resident)
//     + depth-4 B-fragment register pipeline with start-burst.

typedef __bf16 bf16_t;
typedef __bf16 bf16x4 __attribute__((ext_vector_type(4)));
typedef __bf16 bf16x8 __attribute__((ext_vector_type(8)));
typedef float f32x4 __attribute__((ext_vector_type(4)));

#define NB 16384
#define NA 16
#define ND 256
#define BM 64   // rows per block

// XOR swizzle for bf16 LDS tiles [*][256] (row stride 512B): spreads 8-row
// stripes across 8 distinct 16B slots; 16-lane column reads -> 2-way (free).
__device__ __forceinline__ int swz(int r, int c) {
    return r * 256 + (c ^ ((r & 7) << 3));
}

// Per-wave 32(M)x256(K)x64(N) GEMM slice. A from swizzled LDS; B row-major
// [N][K] bf16 from global (L2-resident weights), depth-4 register pipeline.
// C/D layout per m89: col = lane&15, row = (lane>>4)*4 + j.
__device__ __forceinline__ void gemm64(const bf16_t* a_lds, const bf16_t* __restrict__ Bg,
                                       f32x4 acc[2][4], int wr, int wc, int lane)
{
    const int lr = lane & 15, lhi = lane >> 4;
    const int ar0 = wr * 32 + lr;
    const bf16_t* brow = Bg + (wc * 64 + lr) * 256 + lhi * 8;
    bf16x8 bq[4][4];
#pragma unroll
    for (int p = 0; p < 4; ++p)
#pragma unroll
        for (int ni = 0; ni < 4; ++ni)
            bq[p][ni] = *(const bf16x8*)&brow[ni * 4096 + p * 32];
#pragma unroll
    for (int ks = 0; ks < 8; ++ks) {
        const int kc = ks * 32 + lhi * 8;
        bf16x8 af0 = *(const bf16x8*)&a_lds[swz(ar0, kc)];
        bf16x8 af1 = *(const bf16x8*)&a_lds[swz(ar0 + 16, kc)];
#pragma unroll
        for (int ni = 0; ni < 4; ++ni) {
            acc[0][ni] = __builtin_amdgcn_mfma_f32_16x16x32_bf16(af0, bq[ks % 4][ni], acc[0][ni], 0, 0, 0);
            acc[1][ni] = __builtin_amdgcn_mfma_f32_16x16x32_bf16(af1, bq[ks % 4][ni], acc[1][ni], 0, 0, 0);
        }
        if (ks + 4 < 8) {
#pragma unroll
            for (int ni = 0; ni < 4; ++ni)
                bq[ks % 4][ni] = *(const bf16x8*)&brow[ni * 4096 + (ks + 4) * 32];
        }
    }
}

// W_agg [D][2D] fp32 -> W1 [D][D] bf16 (k-major), W2 [D][D] bf16.
__global__ void prep_w(const float* __restrict__ W, bf16_t* __restrict__ W1, bf16_t* __restrict__ W2)
{
    int o = blockIdx.x;
    int k = threadIdx.x;
    W1[o * 256 + k] = (bf16_t)W[o * 512 + k];
    W2[o * 256 + k] = (bf16_t)W[o * 512 + 256 + k];
}

// P[a][i][j] fp32 -> Pt[a][j][i] bf16 via LDS 32x32 tile transpose.
__global__ void transpose_P(const float* __restrict__ Pf, const float* __restrict__ Pb,
                            bf16_t* __restrict__ Pft, bf16_t* __restrict__ Pbt)
{
    __shared__ float t[32][33];
    int blk = blockIdx.x;
    int mat = blk >> 10;
    int rest = blk & 1023;
    int a = rest >> 6;
    int tile = rest & 63;
    int i0 = (tile >> 3) * 32;
    int j0 = (tile & 7) * 32;
    const float* src = (mat ? Pb : Pf) + a * 65536;
    bf16_t* dst = (mat ? Pbt : Pft) + a * 65536;
    int r = threadIdx.x >> 5, c = threadIdx.x & 31;
#pragma unroll
    for (int it = 0; it < 4; ++it)
        t[r + 8 * it][c] = src[(i0 + r + 8 * it) * 256 + j0 + c];
    __syncthreads();
#pragma unroll
    for (int it = 0; it < 4; ++it)
        dst[(j0 + r + 8 * it) * 256 + i0 + c] = (bf16_t)t[c][r + 8 * it];
}

__global__ __launch_bounds__(512, 2)
void fused_main(const float* __restrict__ img, const float* __restrict__ bias,
                const float* __restrict__ edge,
                const bf16_t* __restrict__ W1, const bf16_t* __restrict__ W2,
                const bf16_t* __restrict__ Pf, const bf16_t* __restrict__ Pb,
                const float* __restrict__ sw, float* __restrict__ out)
{
    __shared__ bf16_t E[2][BM * 256];  // 2 x 32 KB edge double-buffer
    __shared__ bf16_t G[BM * 256];     // 32 KB agg tile
    __shared__ bf16_t R[BM * 256];     // 32 KB attr tile

    const int tid = threadIdx.x;
    const int lane = tid & 63;
    const int wid = tid >> 6;
    const int wr = wid >> 2;            // 0..1: 32-row band
    const int wc = wid & 3;             // 0..3: 64-col slice
    const int lr = lane & 15;
    const int lhi = lane >> 4;
    const int brow0 = blockIdx.x * BM;
    const int srr = tid >> 6;           // staging row base 0..7
    const int sc4 = (tid & 63) * 4;     // staging col 0..252

    f32x4 ev[8];

    // nt loads: edge is read exactly once grid-wide; don't pollute L2.
#define EDGE_ISSUE(A_) { \
    const float* ep = edge + (size_t)(brow0 + srr) * (NA * ND) + (size_t)(A_) * ND + sc4; \
    _Pragma("unroll") \
    for (int it = 0; it < 8; ++it) \
        ev[it] = __builtin_nontemporal_load((const f32x4*)(ep + (size_t)it * 8 * (NA * ND))); }

#define EDGE_COMMIT(B_) { \
    bf16_t* eb = &E[B_][0]; \
    _Pragma("unroll") \
    for (int it = 0; it < 8; ++it) { \
        bf16x4 s = {(bf16_t)ev[it].x, (bf16_t)ev[it].y, (bf16_t)ev[it].z, (bf16_t)ev[it].w}; \
        *(bf16x4*)&eb[swz(srr + it * 8, sc4)] = s; \
    } }

    // ---- prologue: stage img -> E[0], T = img @ W1^T + bias (kept in regs) ----
#pragma unroll
    for (int it = 0; it < 8; ++it) {
        int r = srr + it * 8;
        f32x4 v = __builtin_nontemporal_load((const f32x4*)&img[(size_t)(brow0 + r) * ND + sc4]);
        bf16x4 s = {(bf16_t)v.x, (bf16_t)v.y, (bf16_t)v.z, (bf16_t)v.w};
        *(bf16x4*)&E[0][swz(r, sc4)] = s;
    }
    __syncthreads();

    EDGE_ISSUE(0);

    f32x4 T[2][4];
#pragma unroll
    for (int ni = 0; ni < 4; ++ni) {
        float bz = bias[wc * 64 + ni * 16 + lr];
        T[0][ni] = (f32x4){bz, bz, bz, bz};
        T[1][ni] = (f32x4){bz, bz, bz, bz};
    }
    gemm64(&E[0][0], W1, T, wr, wc, lane);
    __syncthreads();           // all waves done reading img from E[0]

    EDGE_COMMIT(0);
    __syncthreads();

    f32x4 indiv[2][4];
#pragma unroll
    for (int mi = 0; mi < 2; ++mi)
#pragma unroll
        for (int ni = 0; ni < 4; ++ni)
            indiv[mi][ni] = (f32x4){0.f, 0.f, 0.f, 0.f};

    for (int a = 0; a < NA; ++a) {
        const int cur = a & 1;
        f32x4 acc[2][4];

        // ---- phase 1: agg = T + edge @ W2^T; issue edge(a+1) loads under it ----
        if (a + 1 < NA) EDGE_ISSUE(a + 1);
#pragma unroll
        for (int mi = 0; mi < 2; ++mi)
#pragma unroll
            for (int ni = 0; ni < 4; ++ni)
                acc[mi][ni] = T[mi][ni];
        gemm64(&E[cur][0], W2, acc, wr, wc, lane);
#pragma unroll
        for (int mi = 0; mi < 2; ++mi)
#pragma unroll
            for (int ni = 0; ni < 4; ++ni)
#pragma unroll
                for (int j = 0; j < 4; ++j)
                    G[swz(wr * 32 + mi * 16 + lhi * 4 + j, wc * 64 + ni * 16 + lr)] = (bf16_t)acc[mi][ni][j];
        __syncthreads();

        // ---- phase 2: attr = agg @ P_fwd[a] -> out (nt) + R ----
#pragma unroll
        for (int mi = 0; mi < 2; ++mi)
#pragma unroll
            for (int ni = 0; ni < 4; ++ni)
                acc[mi][ni] = (f32x4){0.f, 0.f, 0.f, 0.f};
        gemm64(&G[0], Pf + (size_t)a * 65536, acc, wr, wc, lane);
        {
            float* op = out + (size_t)brow0 * (NA * ND) + (size_t)a * ND;
#pragma unroll
            for (int mi = 0; mi < 2; ++mi)
#pragma unroll
                for (int ni = 0; ni < 4; ++ni)
#pragma unroll
                    for (int j = 0; j < 4; ++j) {
                        int r = wr * 32 + mi * 16 + lhi * 4 + j;
                        int c = wc * 64 + ni * 16 + lr;
                        float v = acc[mi][ni][j];
                        __builtin_nontemporal_store(v, &op[(size_t)r * (NA * ND) + c]);
                        R[swz(r, c)] = (bf16_t)v;
                    }
        }
        __syncthreads();

        // ---- phase 3: proj = relu(attr @ P_bwd[a]); indiv += proj * sw[a];
        //      commit edge(a+1) into the other E buffer ----
#pragma unroll
        for (int mi = 0; mi < 2; ++mi)
#pragma unroll
            for (int ni = 0; ni < 4; ++ni)
                acc[mi][ni] = (f32x4){0.f, 0.f, 0.f, 0.f};
        gemm64(&R[0], Pb + (size_t)a * 65536, acc, wr, wc, lane);
        const float swa = sw[a];
#pragma unroll
        for (int mi = 0; mi < 2; ++mi)
#pragma unroll
            for (int ni = 0; ni < 4; ++ni)
#pragma unroll
                for (int j = 0; j < 4; ++j)
                    indiv[mi][ni][j] += fmaxf(acc[mi][ni][j], 0.f) * swa;
        if (a + 1 < NA) EDGE_COMMIT(cur ^ 1);
        __syncthreads();
    }

    // individual_embeddings (nt: written once, never re-read)
#pragma unroll
    for (int mi = 0; mi < 2; ++mi)
#pragma unroll
        for (int ni = 0; ni < 4; ++ni)
#pragma unroll
            for (int j = 0; j < 4; ++j) {
                int r = wr * 32 + mi * 16 + lhi * 4 + j;
                int c = wc * 64 + ni * 16 + lr;
                __builtin_nontemporal_store(indiv[mi][ni][j],
                    &out[(size_t)NB * NA * ND + (size_t)(brow0 + r) * ND + c]);
            }
#undef EDGE_ISSUE
#undef EDGE_COMMIT
}

extern "C" void kernel_launch(void* const* d_in, const int* in_sizes, int n_in,
                              void* d_out, int out_size, void* d_ws, size_t ws_size,
                              hipStream_t stream)
{
    const float* img  = (const float*)d_in[0];
    const float* edge = (const float*)d_in[1];
    const float* Wagg = (const float*)d_in[2];
    const float* bagg = (const float*)d_in[3];
    const float* Pf   = (const float*)d_in[4];
    const float* Pb   = (const float*)d_in[5];
    const float* sw   = (const float*)d_in[6];
    float* out = (float*)d_out;

    char* ws = (char*)d_ws;
    bf16_t* W1  = (bf16_t*)(ws);                       // 128 KB
    bf16_t* W2  = (bf16_t*)(ws + 131072);              // 128 KB
    bf16_t* Pft = (bf16_t*)(ws + 262144);              // 2 MB
    bf16_t* Pbt = (bf16_t*)(ws + 2359296);             // 2 MB

    prep_w<<<256, 256, 0, stream>>>(Wagg, W1, W2);
    transpose_P<<<2048, 256, 0, stream>>>(Pf, Pb, Pft, Pbt);
    fused_main<<<NB / BM, 512, 0, stream>>>(img, bagg, edge, W1, W2, Pft, Pbt, sw, out);
}